// Round 24
// baseline (224.632 us; speedup 1.0000x reference)
//
#include <hip/hip_runtime.h>

typedef unsigned short u16;
typedef __attribute__((ext_vector_type(8))) short short8;
typedef __attribute__((ext_vector_type(4))) float f32x4;

__device__ __forceinline__ u16 f2bf(float f) {
  unsigned u = __float_as_uint(f);
  return (u16)((u + 0x7FFFu + ((u >> 16) & 1u)) >> 16);
}
__device__ __forceinline__ float bf2f(u16 h) {
  return __uint_as_float(((unsigned)h) << 16);
}
__device__ __forceinline__ unsigned cvt_pk_bf16(float lo, float hi) {
  unsigned r;
  asm("v_cvt_pk_bf16_f32 %0, %1, %2" : "=v"(r) : "v"(lo), "v"(hi));
  return r;
}

__device__ __forceinline__ void gload_lds16(const void* g, void* l) {
  __builtin_amdgcn_global_load_lds(
      (const __attribute__((address_space(1))) unsigned*)g,
      (__attribute__((address_space(3))) unsigned*)l, 16, 0, 0);
}

// ------- fused cast fp32 -> bf16 (hs, Wq, Wk, Wv, Wo) + RoPE tables, ONE launch -------
__global__ void cast_all_k(const float4* __restrict__ hs, const float4* __restrict__ Wq,
                           const float4* __restrict__ Wk, const float4* __restrict__ Wv,
                           const float4* __restrict__ Wo,
                           u16* __restrict__ hs_bf, u16* __restrict__ wqkv_bf,
                           u16* __restrict__ wo_bf,
                           float* __restrict__ cosT, float* __restrict__ sinT) {
  int blk = blockIdx.x;
  if (blk >= 20480) {                         // RoPE tables: 512 blocks
    int idx = (blk - 20480) * 256 + threadIdx.x;   // S*64 entries
    int i = idx & 63, s = idx >> 6;
    double inv = pow(10000.0, -(double)(2 * i) / 128.0);
    double f = (double)s * inv;
    cosT[idx] = (float)cos(f);
    sinT[idx] = (float)sin(f);
    return;
  }
  int i = blk * 256 + threadIdx.x;            // float4 index, 0 .. 5242880
  const float4* src; u16* dst; int off;
  if (i < 2097152)      { src = hs; dst = hs_bf;   off = i; }
  else if (i < 3145728) { src = Wq; dst = wqkv_bf; off = i - 2097152; }
  else if (i < 3670016) { src = Wk; dst = wqkv_bf + (size_t)2048 * 2048; off = i - 3145728; }
  else if (i < 4194304) { src = Wv; dst = wqkv_bf + (size_t)3072 * 2048; off = i - 3670016; }
  else                  { src = Wo; dst = wo_bf;   off = i - 4194304; }
  float4 v = src[off];
  union { u16 u[4]; uint2 d; } r;
  r.u[0] = f2bf(v.x); r.u[1] = f2bf(v.y); r.u[2] = f2bf(v.z); r.u[3] = f2bf(v.w);
  *reinterpret_cast<uint2*>(dst + (size_t)off * 4) = r.d;
}

// ---------------- merged prep: K rope+repack AND V transpose in ONE launch ----------------
__global__ void prep_kv_k(const u16* __restrict__ qkv, u16* __restrict__ kt,
                          u16* __restrict__ vt,
                          const float* __restrict__ cosT, const float* __restrict__ sinT) {
  __shared__ u16 tile[128][129];
  int blk = blockIdx.x;
  if (blk < 8192) {
    int idx = blk * 256 + threadIdx.x;   // M*8*64 threads
    int i = idx & 63;
    int kvh = (idx >> 6) & 7;
    int row = idx >> 9;                  // b*S + s
    int s = row & 2047, b = row >> 11;
    size_t src = (size_t)row * 4096 + 2048 + kvh * 128;
    float x1 = bf2f(qkv[src + i]);
    float x2 = bf2f(qkv[src + i + 64]);
    float c = cosT[s * 64 + i], sn = sinT[s * 64 + i];
    size_t dst = ((size_t)(b * 8 + kvh) * 2048 + s) * 128;
    kt[dst + i]      = f2bf(x1 * c - x2 * sn);
    kt[dst + i + 64] = f2bf(x2 * c + x1 * sn);
  } else {
    int bxx = blk - 8192;                // 0..255
    int s0 = (bxx & 15) * 128;
    int bn = bxx >> 4;                   // b*8 + n
    int b = bn >> 3, n = bn & 7;
    for (int e = threadIdx.x; e < 128 * 128; e += 256) {
      int r = e >> 7, c = e & 127;
      tile[r][c] = qkv[(size_t)(b * 2048 + s0 + r) * 4096 + 3072 + n * 128 + c];
    }
    __syncthreads();
    for (int e = threadIdx.x; e < 128 * 128; e += 256) {
      int r = e >> 7, c = e & 127;
      vt[((size_t)bn * 128 + r) * 2048 + s0 + c] = tile[c][r];
    }
  }
}

// ------- GEMM BM=256 x BN={256,128} PHASED: 4 phases/K-tile, half-pass staging -------
// r18 schedule. Stage order per tile t+1: ph0: A-ks0, ph1: B-ks0, ph2: A-ks1, ph3: B-ks1.
// A half-pass = 2 loads/thread; B half-pass = BITER = BN/128 loads (2 or 1; BITER*512 = BN*4
// chunks exactly). Gates (ph0/ph2): leave the 3 newest half-passes in flight ->
// BN=256: vmcnt(6); BN=128: vmcnt(5). Last tile: ph0 -> 4 / 3; ph2 -> 0.
template<typename OutT, int BN>
__global__ __launch_bounds__(512, 1) void gemm256p_k(
    const u16* __restrict__ A, const u16* __restrict__ Bm,
    OutT* __restrict__ C, int M, int N, int K)
{
  constexpr int NFR = BN / 64;              // n-frags per wave (4 or 2)
  constexpr int BITER = BN / 128;           // B half-pass iterations (2 or 1)
  __shared__ __align__(16) u16 As[2][2][256 * 32];
  __shared__ __align__(16) u16 Bs[2][2][BN * 32];
  const int tid = threadIdx.x;
  const int wave = tid >> 6, lane = tid & 63;
  const int wm = wave >> 2, wn = wave & 3;
  const int lrow = lane & 15, lgrp = lane >> 4;
  const int gx = (int)gridDim.x;
  const int nwg = gx * (int)gridDim.y;
  const int f = (int)(blockIdx.y * gridDim.x + blockIdx.x);
  const int sw = (f & 7) * (nwg >> 3) + (f >> 3);
  const int bx = sw % gx, by = sw / gx;
  const int row0 = by * 256, col0 = bx * BN;

  f32x4 acc[8][NFR];
  #pragma unroll
  for (int m = 0; m < 8; ++m)
    #pragma unroll
    for (int n = 0; n < NFR; ++n) acc[m][n] = (f32x4){0.f, 0.f, 0.f, 0.f};

  const int NT = K >> 6;
  const int psw = lgrp ^ (lrow & 3);

  auto stageA = [&](int buf, int t, int ks) {
    const int k0 = (t << 6) + ks * 32;
    #pragma unroll
    for (int i = 0; i < 2; ++i) {
      int s = i * 512 + tid;
      int row = s >> 2, p = s & 3;
      int g = p ^ (row & 3);
      gload_lds16(A + (size_t)(row0 + row) * K + k0 + g * 8,
                  &As[buf][ks][(size_t)(i * 512 + wave * 64) * 8]);
    }
  };
  auto stageB = [&](int buf, int t, int ks) {
    const int k0 = (t << 6) + ks * 32;
    #pragma unroll
    for (int i = 0; i < BITER; ++i) {
      int s = i * 512 + tid;
      int row = s >> 2, p = s & 3;
      int g = p ^ (row & 3);
      gload_lds16(Bm + (size_t)(col0 + row) * K + k0 + g * 8,
                  &Bs[buf][ks][(size_t)(i * 512 + wave * 64) * 8]);
    }
  };

  stageA(0, 0, 0); stageB(0, 0, 0); stageA(0, 0, 1); stageB(0, 0, 1);

  for (int t = 0; t < NT; ++t) {
    const int cur = t & 1, nxt = cur ^ 1;
    const bool pf = (t + 1 < NT);
    short8 af[4], bfr[NFR];

    // ---- ph0: ks0, m0..3 ----
    if (pf) {
      stageA(nxt, t + 1, 0);
      if constexpr (BN == 256) asm volatile("s_waitcnt vmcnt(6)" ::: "memory");
      else                     asm volatile("s_waitcnt vmcnt(5)" ::: "memory");
    } else {
      if constexpr (BN == 256) asm volatile("s_waitcnt vmcnt(4)" ::: "memory");
      else                     asm volatile("s_waitcnt vmcnt(3)" ::: "memory");
    }
    __builtin_amdgcn_s_barrier();
    __builtin_amdgcn_sched_barrier(0);
    #pragma unroll
    for (int m = 0; m < 4; ++m)
      af[m] = *reinterpret_cast<const short8*>(&As[cur][0][(wm * 128 + m * 16 + lrow) * 32 + psw * 8]);
    #pragma unroll
    for (int n = 0; n < NFR; ++n)
      bfr[n] = *reinterpret_cast<const short8*>(&Bs[cur][0][(wn * (NFR * 16) + n * 16 + lrow) * 32 + psw * 8]);
    asm volatile("s_waitcnt lgkmcnt(0)" ::: "memory");
    __builtin_amdgcn_sched_barrier(0);
    __builtin_amdgcn_s_setprio(1);
    #pragma unroll
    for (int m = 0; m < 4; ++m)
      #pragma unroll
      for (int n = 0; n < NFR; ++n)
        acc[m][n] = __builtin_amdgcn_mfma_f32_16x16x32_bf16(af[m], bfr[n], acc[m][n], 0, 0, 0);
    __builtin_amdgcn_s_setprio(0);

    // ---- ph1: ks0, m4..7 ----
    if (pf) stageB(nxt, t + 1, 0);
    #pragma unroll
    for (int m = 0; m < 4; ++m)
      af[m] = *reinterpret_cast<const short8*>(&As[cur][0][(wm * 128 + (m + 4) * 16 + lrow) * 32 + psw * 8]);
    asm volatile("s_waitcnt lgkmcnt(0)" ::: "memory");
    __builtin_amdgcn_sched_barrier(0);
    __builtin_amdgcn_s_setprio(1);
    #pragma unroll
    for (int m = 0; m < 4; ++m)
      #pragma unroll
      for (int n = 0; n < NFR; ++n)
        acc[m + 4][n] = __builtin_amdgcn_mfma_f32_16x16x32_bf16(af[m], bfr[n], acc[m + 4][n], 0, 0, 0);
    __builtin_amdgcn_s_setprio(0);

    // ---- ph2: ks1, m0..3 ----
    if (pf) {
      stageA(nxt, t + 1, 1);
      if constexpr (BN == 256) asm volatile("s_waitcnt vmcnt(6)" ::: "memory");
      else                     asm volatile("s_waitcnt vmcnt(5)" ::: "memory");
    } else {
      asm volatile("s_waitcnt vmcnt(0)" ::: "memory");
    }
    __builtin_amdgcn_s_barrier();
    __builtin_amdgcn_sched_barrier(0);
    #pragma unroll
    for (int m = 0; m < 4; ++m)
      af[m] = *reinterpret_cast<const short8*>(&As[cur][1][(wm * 128 + m * 16 + lrow) * 32 + psw * 8]);
    #pragma unroll
    for (int n = 0; n < NFR; ++n)
      bfr[n] = *reinterpret_cast<const short8*>(&Bs[cur][1][(wn * (NFR * 16) + n * 16 + lrow) * 32 + psw * 8]);
    asm volatile("s_waitcnt lgkmcnt(0)" ::: "memory");
    __builtin_amdgcn_sched_barrier(0);
    __builtin_amdgcn_s_setprio(1);
    #pragma unroll
    for (int m = 0; m < 4; ++m)
      #pragma unroll
      for (int n = 0; n < NFR; ++n)
        acc[m][n] = __builtin_amdgcn_mfma_f32_16x16x32_bf16(af[m], bfr[n], acc[m][n], 0, 0, 0);
    __builtin_amdgcn_s_setprio(0);

    // ---- ph3: ks1, m4..7 ----
    if (pf) stageB(nxt, t + 1, 1);
    #pragma unroll
    for (int m = 0; m < 4; ++m)
      af[m] = *reinterpret_cast<const short8*>(&As[cur][1][(wm * 128 + (m + 4) * 16 + lrow) * 32 + psw * 8]);
    asm volatile("s_waitcnt lgkmcnt(0)" ::: "memory");
    __builtin_amdgcn_sched_barrier(0);
    __builtin_amdgcn_s_setprio(1);
    #pragma unroll
    for (int m = 0; m < 4; ++m)
      #pragma unroll
      for (int n = 0; n < NFR; ++n)
        acc[m + 4][n] = __builtin_amdgcn_mfma_f32_16x16x32_bf16(af[m], bfr[n], acc[m + 4][n], 0, 0, 0);
    __builtin_amdgcn_s_setprio(0);
  }

  #pragma unroll
  for (int m = 0; m < 8; ++m)
    #pragma unroll
    for (int n = 0; n < NFR; ++n)
      #pragma unroll
      for (int j = 0; j < 4; ++j) {
        int r = row0 + wm * 128 + m * 16 + lgrp * 4 + j;
        int col = col0 + wn * (NFR * 16) + n * 16 + lrow;
        float val = acc[m][n][j];
        if constexpr (sizeof(OutT) == 2) C[(size_t)r * N + col] = f2bf(val);
        else                             C[(size_t)r * N + col] = val;
      }
}

// ---------------- causal GQA flash attention (v8 + fused in-register Q-RoPE; r20 best) ----
__global__ __launch_bounds__(256, 2) void flash_attn_k(
    const u16* __restrict__ qkv, const u16* __restrict__ kt,
    const u16* __restrict__ vt, u16* __restrict__ o,
    const float* __restrict__ cosT, const float* __restrict__ sinT)
{
  constexpr int S = 2048, NH = 16, NKV = 8, D = 128;
  const int wave = threadIdx.x >> 6, lane = threadIdx.x & 63;
  const int flat = blockIdx.x;
  const int pr = flat >> 5;                            // 0..15
  const int bh = (flat & 7) * 4 + ((flat >> 3) & 3);   // XCD-local heads
  const int b = bh >> 4, h = bh & 15;
  const int kvh = h >> 1;
  const int lrow = lane & 15, lgrp = lane >> 4;

  __shared__ __align__(16) u16 ks[2][64 * 128];   // K tile (row=kv, swz)
  __shared__ __align__(16) u16 vs[2][128 * 64];   // V^T tile (row=d, swz)

  const float scl2 = 0.12754245006443634f;        // log2(e)/sqrt(128)
  const u16* khead = kt + (size_t)(b * NKV + kvh) * S * D;
  const u16* vhead = vt + (size_t)(b * NKV + kvh) * D * S;

  const int srcA = lrow + 16 * ((2 * lgrp) & 3);
  const int srcB = srcA + 16;
  const bool hiSel = (lgrp >= 2);

  auto stage = [&](int nxt, int kv0n) {
    #pragma unroll
    for (int i = 0; i < 4; ++i) {
      int c = i * 256 + wave * 64 + lane;
      int kr = c >> 4;
      int kc16 = (c & 15) ^ (kr & 7);
      gload_lds16(khead + (size_t)(kv0n + kr) * D + kc16 * 8,
                  &ks[nxt][(size_t)(i * 256 + wave * 64) * 8]);
      int vr = c >> 3;
      int vc = (c & 7) ^ (vr & 7);
      gload_lds16(vhead + (size_t)vr * S + kv0n + vc * 8,
                  &vs[nxt][(size_t)(i * 256 + wave * 64) * 8]);
    }
  };

  #pragma unroll
  for (int ph = 0; ph < 2; ++ph) {
    const int qt = ph ? pr : (31 - pr);
    const int q0 = qt * 64 + wave * 16;
    const int trips = qt + 1;

    short8 qf[4];   // Q rows: lane's B-frag (q=lrow, k-chunk lgrp*8)
    const int srow = q0 + lrow;
    const u16* qbase = qkv + (size_t)(b * S + srow) * 4096 + h * 128;
    #pragma unroll
    for (int kc = 0; kc < 4; ++kc)
      qf[kc] = *reinterpret_cast<const short8*>(qbase + kc * 32 + lgrp * 8);
    // in-register RoPE: qf[kc2] (i = kc2*32+lgrp*8+e) pairs with qf[kc2+2] (i+64)
    #pragma unroll
    for (int kc2 = 0; kc2 < 2; ++kc2) {
      const float* cp = &cosT[srow * 64 + kc2 * 32 + lgrp * 8];
      const float* sp = &sinT[srow * 64 + kc2 * 32 + lgrp * 8];
      float4 c0 = *reinterpret_cast<const float4*>(cp);
      float4 c1 = *reinterpret_cast<const float4*>(cp + 4);
      float4 s0 = *reinterpret_cast<const float4*>(sp);
      float4 s1 = *reinterpret_cast<const float4*>(sp + 4);
      float cc[8] = {c0.x, c0.y, c0.z, c0.w, c1.x, c1.y, c1.z, c1.w};
      float ss[8] = {s0.x, s0.y, s0.z, s0.w, s1.x, s1.y, s1.z, s1.w};
      #pragma unroll
      for (int e = 0; e < 8; ++e) {
        float x1 = bf2f((u16)qf[kc2][e]);
        float x2 = bf2f((u16)qf[kc2 + 2][e]);
        qf[kc2][e]     = (short)f2bf(x1 * cc[e] - x2 * ss[e]);
        qf[kc2 + 2][e] = (short)f2bf(x2 * cc[e] + x1 * ss[e]);
      }
    }

    f32x4 acc[8];   // O^T frags: acc[n][j] = O[d=n*16+lgrp*4+j][q=lrow]
    #pragma unroll
    for (int n = 0; n < 8; ++n) acc[n] = (f32x4){0.f, 0.f, 0.f, 0.f};
    float l_part = 0.f;

    stage(0, 0);

    for (int t = 0; t < trips; ++t) {
      const int cur = t & 1;
      asm volatile("s_waitcnt vmcnt(0)" ::: "memory");
      __builtin_amdgcn_s_barrier();
      __builtin_amdgcn_sched_barrier(0);
      // --- QK^T swapped: sc[nb] = P^T frag (rows kv, col q) ---
      f32x4 sc[4];
      #pragma unroll
      for (int nb = 0; nb < 4; ++nb) {
        sc[nb] = (f32x4){0.f, 0.f, 0.f, 0.f};
        const int r = nb * 16 + lrow;
        #pragma unroll
        for (int kc = 0; kc < 4; ++kc) {
          int ch = (kc * 4 + lgrp) ^ (r & 7);
          short8 kf = *reinterpret_cast<const short8*>(&ks[cur][r * 128 + ch * 8]);
          sc[nb] = __builtin_amdgcn_mfma_f32_16x16x32_bf16(kf, qf[kc], sc[nb], 0, 0, 0);
        }
      }
      if (t + 1 < trips) stage(cur ^ 1, (t + 1) * 64);
      // --- mask + exp2 (lane-local: kv = nb*16+lgrp*4+j, q = lrow) ---
      float p[4][4];
      if (t < trips - 1) {
        #pragma unroll
        for (int nb = 0; nb < 4; ++nb)
          #pragma unroll
          for (int j = 0; j < 4; ++j)
            p[nb][j] = exp2f(fminf(sc[nb][j] * scl2, 43.f));
      } else {
        #pragma unroll
        for (int nb = 0; nb < 4; ++nb) {
          if (nb < wave) {
            #pragma unroll
            for (int j = 0; j < 4; ++j)
              p[nb][j] = exp2f(fminf(sc[nb][j] * scl2, 43.f));
          } else if (nb == wave) {
            #pragma unroll
            for (int j = 0; j < 4; ++j)
              p[nb][j] = (lgrp * 4 + j <= lrow) ? exp2f(fminf(sc[nb][j] * scl2, 43.f)) : 0.f;
          } else {
            #pragma unroll
            for (int j = 0; j < 4; ++j) p[nb][j] = 0.f;
          }
        }
      }
      #pragma unroll
      for (int nb = 0; nb < 4; ++nb)
        #pragma unroll
        for (int j = 0; j < 4; ++j) l_part += p[nb][j];
      // --- pack to bf16 pairs ---
      unsigned pk[4][2];
      #pragma unroll
      for (int nb = 0; nb < 4; ++nb) {
        pk[nb][0] = cvt_pk_bf16(p[nb][0], p[nb][1]);
        pk[nb][1] = cvt_pk_bf16(p[nb][2], p[nb][3]);
      }
      // --- redistribute to B-frag layout ---
      short8 pfB[2];
      #pragma unroll
      for (int half = 0; half < 2; ++half) {
        unsigned lo0 = __shfl(pk[2 * half][0], srcA), hi0 = __shfl(pk[2 * half + 1][0], srcA);
        unsigned lo1 = __shfl(pk[2 * half][1], srcA), hi1 = __shfl(pk[2 * half + 1][1], srcA);
        unsigned lo2 = __shfl(pk[2 * half][0], srcB), hi2 = __shfl(pk[2 * half + 1][0], srcB);
        unsigned lo3 = __shfl(pk[2 * half][1], srcB), hi3 = __shfl(pk[2 * half + 1][1], srcB);
        union { unsigned u[4]; short8 s8; } asm_u;
        asm_u.u[0] = hiSel ? hi0 : lo0;
        asm_u.u[1] = hiSel ? hi1 : lo1;
        asm_u.u[2] = hiSel ? hi2 : lo2;
        asm_u.u[3] = hiSel ? hi3 : lo3;
        pfB[half] = asm_u.s8;
      }
      // --- PV: acc^T[d][q] += V^T[d][kv] * P[q][kv] ---
      #pragma unroll
      for (int n = 0; n < 8; ++n) {
        const int d = n * 16 + lrow;
        #pragma unroll
        for (int kc2 = 0; kc2 < 2; ++kc2) {
          int ch = (kc2 * 4 + lgrp) ^ (d & 7);
          short8 vf = *reinterpret_cast<const short8*>(&vs[cur][d * 64 + ch * 8]);
          acc[n] = __builtin_amdgcn_mfma_f32_16x16x32_bf16(vf, pfB[kc2], acc[n], 0, 0, 0);
        }
      }
    }

    // reduce l over the 4 lgrp partners of this q, normalize, packed 8B stores
    float s = l_part;
    s += __shfl_xor(s, 16);
    s += __shfl_xor(s, 32);
    float inv = 1.f / s;
    u16* obase = o + (((size_t)(b * S + q0 + lrow)) * NH + h) * D;
    #pragma unroll
    for (int n = 0; n < 8; ++n) {
      uint2 wv;
      wv.x = cvt_pk_bf16(acc[n][0] * inv, acc[n][1] * inv);
      wv.y = cvt_pk_bf16(acc[n][2] * inv, acc[n][3] * inv);
      *reinterpret_cast<uint2*>(obase + n * 16 + lgrp * 4) = wv;
    }
    __syncthreads();                        // phase A fully drained before phase B restages
  }
}

// ---------------- launch ----------------
extern "C" void kernel_launch(void* const* d_in, const int* in_sizes, int n_in,
                              void* d_out, int out_size, void* d_ws, size_t ws_size,
                              hipStream_t stream) {
  const float* hs = (const float*)d_in[0];
  const float* Wq = (const float*)d_in[1];
  const float* Wk = (const float*)d_in[2];
  const float* Wv = (const float*)d_in[3];
  const float* Wo = (const float*)d_in[4];
  float* out = (float*)d_out;

  constexpr int B = 2, S = 2048, H = 2048, NH = 16, NKV = 8, D = 128;
  constexpr int M = B * S;  // 4096
  constexpr int NQKV = 4096;

  char* w = (char*)d_ws;
  auto alloc = [&](size_t bytes) { char* p = w; w += (bytes + 255) & ~(size_t)255; return p; };
  u16* hs_bf   = (u16*)alloc((size_t)M * H * 2);        // reused as attn later
  u16* wqkv_bf = (u16*)alloc((size_t)NQKV * H * 2);     // reused as vt+kt later
  u16* wo_bf   = (u16*)alloc((size_t)H * H * 2);
  u16* qkv     = (u16*)alloc((size_t)M * NQKV * 2);
  float* cosT  = (float*)alloc((size_t)S * 64 * 4);
  float* sinT  = (float*)alloc((size_t)S * 64 * 4);
  u16* attn = hs_bf;                                    // hs dead after QKV GEMM
  u16* vt   = wqkv_bf;                                  // 8MB
  u16* kt   = wqkv_bf + (size_t)B * NKV * D * S;        // next 8MB (Wqkv slot = 16MB)

  // fused casts + RoPE tables in ONE launch (blocks >= 20480 do the tables)
  cast_all_k<<<20480 + 512, 256, 0, stream>>>(
      (const float4*)hs, (const float4*)Wq, (const float4*)Wk, (const float4*)Wv,
      (const float4*)Wo, hs_bf, wqkv_bf, wo_bf, cosT, sinT);

  // fused QKV projection: qkv[M][4096] (4-phase counted-vmcnt kernel)
  gemm256p_k<u16, 256><<<dim3(NQKV / 256, M / 256), 512, 0, stream>>>(hs_bf, wqkv_bf, qkv, M, NQKV, H);

  // K rope+repack AND V transpose in one launch (Q roped inside flash)
  prep_kv_k<<<8448, 256, 0, stream>>>(qkv, kt, vt, cosT, sinT);

  // attention (writes into old hs slot)
  flash_attn_k<<<512, 256, 0, stream>>>(qkv, kt, vt, attn, cosT, sinT);

  // output projection (fp32 out): 256x128 tile, 4-phase schedule, 256 blocks (full chip)
  gemm256p_k<float, 128><<<dim3(H / 128, M / 256), 512, 0, stream>>>(attn, wo_bf, out, M, H, H);
}

// Round 25
// 220.525 us; speedup vs baseline: 1.0186x; 1.0186x over previous
//
#include <hip/hip_runtime.h>

typedef unsigned short u16;
typedef __attribute__((ext_vector_type(8))) short short8;
typedef __attribute__((ext_vector_type(4))) float f32x4;

__device__ __forceinline__ u16 f2bf(float f) {
  unsigned u = __float_as_uint(f);
  return (u16)((u + 0x7FFFu + ((u >> 16) & 1u)) >> 16);
}
__device__ __forceinline__ float bf2f(u16 h) {
  return __uint_as_float(((unsigned)h) << 16);
}
__device__ __forceinline__ unsigned cvt_pk_bf16(float lo, float hi) {
  unsigned r;
  asm("v_cvt_pk_bf16_f32 %0, %1, %2" : "=v"(r) : "v"(lo), "v"(hi));
  return r;
}

__device__ __forceinline__ void gload_lds16(const void* g, void* l) {
  __builtin_amdgcn_global_load_lds(
      (const __attribute__((address_space(1))) unsigned*)g,
      (__attribute__((address_space(3))) unsigned*)l, 16, 0, 0);
}

// ---------------- fused cast fp32 -> bf16 (hs, Wq, Wk, Wv, Wo in one launch) ----------------
__global__ void cast_all_k(const float4* __restrict__ hs, const float4* __restrict__ Wq,
                           const float4* __restrict__ Wk, const float4* __restrict__ Wv,
                           const float4* __restrict__ Wo,
                           u16* __restrict__ hs_bf, u16* __restrict__ wqkv_bf,
                           u16* __restrict__ wo_bf) {
  int i = blockIdx.x * 256 + threadIdx.x;     // float4 index, 0 .. 5242880
  const float4* src; u16* dst; int off;
  if (i < 2097152)      { src = hs; dst = hs_bf;   off = i; }
  else if (i < 3145728) { src = Wq; dst = wqkv_bf; off = i - 2097152; }
  else if (i < 3670016) { src = Wk; dst = wqkv_bf + (size_t)2048 * 2048; off = i - 3145728; }
  else if (i < 4194304) { src = Wv; dst = wqkv_bf + (size_t)3072 * 2048; off = i - 3670016; }
  else                  { src = Wo; dst = wo_bf;   off = i - 4194304; }
  float4 v = src[off];
  union { u16 u[4]; uint2 d; } r;
  r.u[0] = f2bf(v.x); r.u[1] = f2bf(v.y); r.u[2] = f2bf(v.z); r.u[3] = f2bf(v.w);
  *reinterpret_cast<uint2*>(dst + (size_t)off * 4) = r.d;
}

// ---------------- RoPE tables ----------------
__global__ void rope_tables_k(float* __restrict__ cosT, float* __restrict__ sinT) {
  int idx = blockIdx.x * 256 + threadIdx.x;   // S*64 threads
  int i = idx & 63, s = idx >> 6;
  double inv = pow(10000.0, -(double)(2 * i) / 128.0);
  double f = (double)s * inv;
  cosT[idx] = (float)cos(f);
  sinT[idx] = (float)sin(f);
}

// ---------------- merged prep: K rope+repack AND V transpose in ONE launch ----------------
__global__ void prep_kv_k(const u16* __restrict__ qkv, u16* __restrict__ kt,
                          u16* __restrict__ vt,
                          const float* __restrict__ cosT, const float* __restrict__ sinT) {
  __shared__ u16 tile[128][129];
  int blk = blockIdx.x;
  if (blk < 8192) {
    int idx = blk * 256 + threadIdx.x;   // M*8*64 threads
    int i = idx & 63;
    int kvh = (idx >> 6) & 7;
    int row = idx >> 9;                  // b*S + s
    int s = row & 2047, b = row >> 11;
    size_t src = (size_t)row * 4096 + 2048 + kvh * 128;
    float x1 = bf2f(qkv[src + i]);
    float x2 = bf2f(qkv[src + i + 64]);
    float c = cosT[s * 64 + i], sn = sinT[s * 64 + i];
    size_t dst = ((size_t)(b * 8 + kvh) * 2048 + s) * 128;
    kt[dst + i]      = f2bf(x1 * c - x2 * sn);
    kt[dst + i + 64] = f2bf(x2 * c + x1 * sn);
  } else {
    int bxx = blk - 8192;                // 0..255
    int s0 = (bxx & 15) * 128;
    int bn = bxx >> 4;                   // b*8 + n
    int b = bn >> 3, n = bn & 7;
    for (int e = threadIdx.x; e < 128 * 128; e += 256) {
      int r = e >> 7, c = e & 127;
      tile[r][c] = qkv[(size_t)(b * 2048 + s0 + r) * 4096 + 3072 + n * 128 + c];
    }
    __syncthreads();
    for (int e = threadIdx.x; e < 128 * 128; e += 256) {
      int r = e >> 7, c = e & 127;
      vt[((size_t)bn * 128 + r) * 2048 + s0 + c] = tile[c][r];
    }
  }
}

// ---------------- GEMM 256^2 PHASED (QKV): 4 phases/K-tile, half-pass staging, vmcnt(6) ----
template<typename OutT>
__global__ __launch_bounds__(512, 1) void gemm256p_k(
    const u16* __restrict__ A, const u16* __restrict__ Bm,
    OutT* __restrict__ C, int M, int N, int K)
{
  __shared__ __align__(16) u16 As[2][2][256 * 32];
  __shared__ __align__(16) u16 Bs[2][2][256 * 32];
  const int tid = threadIdx.x;
  const int wave = tid >> 6, lane = tid & 63;
  const int wm = wave >> 2, wn = wave & 3;
  const int lrow = lane & 15, lgrp = lane >> 4;
  const int gx = (int)gridDim.x;
  const int nwg = gx * (int)gridDim.y;
  const int f = (int)(blockIdx.y * gridDim.x + blockIdx.x);
  const int sw = (f & 7) * (nwg >> 3) + (f >> 3);
  const int bx = sw % gx, by = sw / gx;
  const int row0 = by * 256, col0 = bx * 256;

  f32x4 acc[8][4];
  #pragma unroll
  for (int m = 0; m < 8; ++m)
    #pragma unroll
    for (int n = 0; n < 4; ++n) acc[m][n] = (f32x4){0.f, 0.f, 0.f, 0.f};

  const int NT = K >> 6;
  const int psw = lgrp ^ (lrow & 3);

  auto stageA = [&](int buf, int t, int ks) {
    const int k0 = (t << 6) + ks * 32;
    #pragma unroll
    for (int i = 0; i < 2; ++i) {
      int s = i * 512 + tid;
      int row = s >> 2, p = s & 3;
      int g = p ^ (row & 3);
      gload_lds16(A + (size_t)(row0 + row) * K + k0 + g * 8,
                  &As[buf][ks][(size_t)(i * 512 + wave * 64) * 8]);
    }
  };
  auto stageB = [&](int buf, int t, int ks) {
    const int k0 = (t << 6) + ks * 32;
    #pragma unroll
    for (int i = 0; i < 2; ++i) {
      int s = i * 512 + tid;
      int row = s >> 2, p = s & 3;
      int g = p ^ (row & 3);
      gload_lds16(Bm + (size_t)(col0 + row) * K + k0 + g * 8,
                  &Bs[buf][ks][(size_t)(i * 512 + wave * 64) * 8]);
    }
  };

  stageA(0, 0, 0); stageB(0, 0, 0); stageA(0, 0, 1); stageB(0, 0, 1);

  for (int t = 0; t < NT; ++t) {
    const int cur = t & 1, nxt = cur ^ 1;
    const bool pf = (t + 1 < NT);
    short8 af[4], bfr[4];

    if (pf) { stageA(nxt, t + 1, 0); asm volatile("s_waitcnt vmcnt(6)" ::: "memory"); }
    else    {                        asm volatile("s_waitcnt vmcnt(4)" ::: "memory"); }
    __builtin_amdgcn_s_barrier();
    __builtin_amdgcn_sched_barrier(0);
    #pragma unroll
    for (int m = 0; m < 4; ++m)
      af[m] = *reinterpret_cast<const short8*>(&As[cur][0][(wm * 128 + m * 16 + lrow) * 32 + psw * 8]);
    #pragma unroll
    for (int n = 0; n < 4; ++n)
      bfr[n] = *reinterpret_cast<const short8*>(&Bs[cur][0][(wn * 64 + n * 16 + lrow) * 32 + psw * 8]);
    asm volatile("s_waitcnt lgkmcnt(0)" ::: "memory");
    __builtin_amdgcn_sched_barrier(0);
    __builtin_amdgcn_s_setprio(1);
    #pragma unroll
    for (int m = 0; m < 4; ++m)
      #pragma unroll
      for (int n = 0; n < 4; ++n)
        acc[m][n] = __builtin_amdgcn_mfma_f32_16x16x32_bf16(af[m], bfr[n], acc[m][n], 0, 0, 0);
    __builtin_amdgcn_s_setprio(0);

    if (pf) stageB(nxt, t + 1, 0);
    #pragma unroll
    for (int m = 0; m < 4; ++m)
      af[m] = *reinterpret_cast<const short8*>(&As[cur][0][(wm * 128 + (m + 4) * 16 + lrow) * 32 + psw * 8]);
    asm volatile("s_waitcnt lgkmcnt(0)" ::: "memory");
    __builtin_amdgcn_sched_barrier(0);
    __builtin_amdgcn_s_setprio(1);
    #pragma unroll
    for (int m = 0; m < 4; ++m)
      #pragma unroll
      for (int n = 0; n < 4; ++n)
        acc[m + 4][n] = __builtin_amdgcn_mfma_f32_16x16x32_bf16(af[m], bfr[n], acc[m + 4][n], 0, 0, 0);
    __builtin_amdgcn_s_setprio(0);

    if (pf) { stageA(nxt, t + 1, 1); asm volatile("s_waitcnt vmcnt(6)" ::: "memory"); }
    else    {                        asm volatile("s_waitcnt vmcnt(0)" ::: "memory"); }
    __builtin_amdgcn_s_barrier();
    __builtin_amdgcn_sched_barrier(0);
    #pragma unroll
    for (int m = 0; m < 4; ++m)
      af[m] = *reinterpret_cast<const short8*>(&As[cur][1][(wm * 128 + m * 16 + lrow) * 32 + psw * 8]);
    #pragma unroll
    for (int n = 0; n < 4; ++n)
      bfr[n] = *reinterpret_cast<const short8*>(&Bs[cur][1][(wn * 64 + n * 16 + lrow) * 32 + psw * 8]);
    asm volatile("s_waitcnt lgkmcnt(0)" ::: "memory");
    __builtin_amdgcn_sched_barrier(0);
    __builtin_amdgcn_s_setprio(1);
    #pragma unroll
    for (int m = 0; m < 4; ++m)
      #pragma unroll
      for (int n = 0; n < 4; ++n)
        acc[m][n] = __builtin_amdgcn_mfma_f32_16x16x32_bf16(af[m], bfr[n], acc[m][n], 0, 0, 0);
    __builtin_amdgcn_s_setprio(0);

    if (pf) stageB(nxt, t + 1, 1);
    #pragma unroll
    for (int m = 0; m < 4; ++m)
      af[m] = *reinterpret_cast<const short8*>(&As[cur][1][(wm * 128 + (m + 4) * 16 + lrow) * 32 + psw * 8]);
    asm volatile("s_waitcnt lgkmcnt(0)" ::: "memory");
    __builtin_amdgcn_sched_barrier(0);
    __builtin_amdgcn_s_setprio(1);
    #pragma unroll
    for (int m = 0; m < 4; ++m)
      #pragma unroll
      for (int n = 0; n < 4; ++n)
        acc[m + 4][n] = __builtin_amdgcn_mfma_f32_16x16x32_bf16(af[m], bfr[n], acc[m + 4][n], 0, 0, 0);
    __builtin_amdgcn_s_setprio(0);
  }

  #pragma unroll
  for (int m = 0; m < 8; ++m)
    #pragma unroll
    for (int n = 0; n < 4; ++n)
      #pragma unroll
      for (int j = 0; j < 4; ++j) {
        int r = row0 + wm * 128 + m * 16 + lgrp * 4 + j;
        int col = col0 + wn * 64 + n * 16 + lrow;
        float val = acc[m][n][j];
        if constexpr (sizeof(OutT) == 2) C[(size_t)r * N + col] = f2bf(val);
        else                             C[(size_t)r * N + col] = val;
      }
}

// ---------------- GEMM BM=256 x BN=128 (O-proj), dbuf BK=64, counted vmcnt, XOR swz ------
template<typename OutT, int BN>
__global__ __launch_bounds__(512, 1) void gemm256_k(
    const u16* __restrict__ A, const u16* __restrict__ Bm,
    OutT* __restrict__ C, int M, int N, int K)
{
  constexpr int BITER = (BN * 8) / 512;
  constexpr int NFR = BN / 64;
  __shared__ __align__(16) u16 As[2][256 * 64];
  __shared__ __align__(16) u16 Bs[2][BN * 64];
  const int tid = threadIdx.x;
  const int wave = tid >> 6, lane = tid & 63;
  const int wm = wave >> 2, wn = wave & 3;
  const int lrow = lane & 15, lgrp = lane >> 4;
  const int gx = (int)gridDim.x;
  const int nwg = gx * (int)gridDim.y;
  const int f = (int)(blockIdx.y * gridDim.x + blockIdx.x);
  const int sw = (f & 7) * (nwg >> 3) + (f >> 3);
  const int bx = sw % gx, by = sw / gx;
  const int row0 = by * 256, col0 = bx * BN;

  f32x4 acc[8][NFR];
  #pragma unroll
  for (int m = 0; m < 8; ++m)
    #pragma unroll
    for (int n = 0; n < NFR; ++n) acc[m][n] = (f32x4){0.f, 0.f, 0.f, 0.f};

  const int NT = K >> 6;

  auto stage = [&](int buf, int k0) {
    #pragma unroll
    for (int i = 0; i < 4; ++i) {
      int cid = i * 512 + tid;
      int row = cid >> 3, cp = cid & 7;
      int c = cp ^ (row & 7);
      gload_lds16(A + (size_t)(row0 + row) * K + k0 + c * 8,
                  &As[buf][(size_t)(i * 512 + wave * 64) * 8]);
    }
    #pragma unroll
    for (int i = 0; i < BITER; ++i) {
      int cid = i * 512 + tid;
      int row = cid >> 3, cp = cid & 7;
      int c = cp ^ (row & 7);
      gload_lds16(Bm + (size_t)(col0 + row) * K + k0 + c * 8,
                  &Bs[buf][(size_t)(i * 512 + wave * 64) * 8]);
    }
  };

  stage(0, 0);
  for (int t = 0; t < NT; ++t) {
    const int cur = t & 1;
    if (t + 1 < NT) {
      stage(cur ^ 1, (t + 1) << 6);
      if constexpr (BN == 256) asm volatile("s_waitcnt vmcnt(8)" ::: "memory");
      else                     asm volatile("s_waitcnt vmcnt(6)" ::: "memory");
    } else {
      asm volatile("s_waitcnt vmcnt(0)" ::: "memory");
    }
    __builtin_amdgcn_s_barrier();
    __builtin_amdgcn_sched_barrier(0);
    #pragma unroll
    for (int ks = 0; ks < 2; ++ks) {
      short8 af[8], bfr[NFR];
      #pragma unroll
      for (int m = 0; m < 8; ++m) {
        int row = wm * 128 + m * 16 + lrow;
        int cp = (ks * 4 + lgrp) ^ (row & 7);
        af[m] = *reinterpret_cast<const short8*>(&As[cur][row * 64 + cp * 8]);
      }
      #pragma unroll
      for (int n = 0; n < NFR; ++n) {
        int row = wn * (NFR * 16) + n * 16 + lrow;
        int cp = (ks * 4 + lgrp) ^ (row & 7);
        bfr[n] = *reinterpret_cast<const short8*>(&Bs[cur][row * 64 + cp * 8]);
      }
      #pragma unroll
      for (int m = 0; m < 8; ++m)
        #pragma unroll
        for (int n = 0; n < NFR; ++n)
          acc[m][n] = __builtin_amdgcn_mfma_f32_16x16x32_bf16(af[m], bfr[n], acc[m][n], 0, 0, 0);
    }
    __builtin_amdgcn_sched_barrier(0);
    __builtin_amdgcn_s_barrier();
  }

  #pragma unroll
  for (int m = 0; m < 8; ++m)
    #pragma unroll
    for (int n = 0; n < NFR; ++n)
      #pragma unroll
      for (int j = 0; j < 4; ++j) {
        int r = row0 + wm * 128 + m * 16 + lgrp * 4 + j;
        int col = col0 + wn * (NFR * 16) + n * 16 + lrow;
        float val = acc[m][n][j];
        if constexpr (sizeof(OutT) == 2) C[(size_t)r * N + col] = f2bf(val);
        else                             C[(size_t)r * N + col] = val;
      }
}

// ---------------- causal GQA flash attention (v8 + fused in-register Q-RoPE; r20 best) ----
__global__ __launch_bounds__(256, 2) void flash_attn_k(
    const u16* __restrict__ qkv, const u16* __restrict__ kt,
    const u16* __restrict__ vt, u16* __restrict__ o,
    const float* __restrict__ cosT, const float* __restrict__ sinT)
{
  constexpr int S = 2048, NH = 16, NKV = 8, D = 128;
  const int wave = threadIdx.x >> 6, lane = threadIdx.x & 63;
  const int flat = blockIdx.x;
  const int pr = flat >> 5;                            // 0..15
  const int bh = (flat & 7) * 4 + ((flat >> 3) & 3);   // XCD-local heads
  const int b = bh >> 4, h = bh & 15;
  const int kvh = h >> 1;
  const int lrow = lane & 15, lgrp = lane >> 4;

  __shared__ __align__(16) u16 ks[2][64 * 128];   // K tile (row=kv, swz)
  __shared__ __align__(16) u16 vs[2][128 * 64];   // V^T tile (row=d, swz)

  const float scl2 = 0.12754245006443634f;        // log2(e)/sqrt(128)
  const u16* khead = kt + (size_t)(b * NKV + kvh) * S * D;
  const u16* vhead = vt + (size_t)(b * NKV + kvh) * D * S;

  const int srcA = lrow + 16 * ((2 * lgrp) & 3);
  const int srcB = srcA + 16;
  const bool hiSel = (lgrp >= 2);

  auto stage = [&](int nxt, int kv0n) {
    #pragma unroll
    for (int i = 0; i < 4; ++i) {
      int c = i * 256 + wave * 64 + lane;
      int kr = c >> 4;
      int kc16 = (c & 15) ^ (kr & 7);
      gload_lds16(khead + (size_t)(kv0n + kr) * D + kc16 * 8,
                  &ks[nxt][(size_t)(i * 256 + wave * 64) * 8]);
      int vr = c >> 3;
      int vc = (c & 7) ^ (vr & 7);
      gload_lds16(vhead + (size_t)vr * S + kv0n + vc * 8,
                  &vs[nxt][(size_t)(i * 256 + wave * 64) * 8]);
    }
  };

  #pragma unroll
  for (int ph = 0; ph < 2; ++ph) {
    const int qt = ph ? pr : (31 - pr);
    const int q0 = qt * 64 + wave * 16;
    const int trips = qt + 1;

    short8 qf[4];   // Q rows: lane's B-frag (q=lrow, k-chunk lgrp*8)
    const int srow = q0 + lrow;
    const u16* qbase = qkv + (size_t)(b * S + srow) * 4096 + h * 128;
    #pragma unroll
    for (int kc = 0; kc < 4; ++kc)
      qf[kc] = *reinterpret_cast<const short8*>(qbase + kc * 32 + lgrp * 8);
    // in-register RoPE: qf[kc2] (i = kc2*32+lgrp*8+e) pairs with qf[kc2+2] (i+64)
    #pragma unroll
    for (int kc2 = 0; kc2 < 2; ++kc2) {
      const float* cp = &cosT[srow * 64 + kc2 * 32 + lgrp * 8];
      const float* sp = &sinT[srow * 64 + kc2 * 32 + lgrp * 8];
      float4 c0 = *reinterpret_cast<const float4*>(cp);
      float4 c1 = *reinterpret_cast<const float4*>(cp + 4);
      float4 s0 = *reinterpret_cast<const float4*>(sp);
      float4 s1 = *reinterpret_cast<const float4*>(sp + 4);
      float cc[8] = {c0.x, c0.y, c0.z, c0.w, c1.x, c1.y, c1.z, c1.w};
      float ss[8] = {s0.x, s0.y, s0.z, s0.w, s1.x, s1.y, s1.z, s1.w};
      #pragma unroll
      for (int e = 0; e < 8; ++e) {
        float x1 = bf2f((u16)qf[kc2][e]);
        float x2 = bf2f((u16)qf[kc2 + 2][e]);
        qf[kc2][e]     = (short)f2bf(x1 * cc[e] - x2 * ss[e]);
        qf[kc2 + 2][e] = (short)f2bf(x2 * cc[e] + x1 * ss[e]);
      }
    }

    f32x4 acc[8];   // O^T frags: acc[n][j] = O[d=n*16+lgrp*4+j][q=lrow]
    #pragma unroll
    for (int n = 0; n < 8; ++n) acc[n] = (f32x4){0.f, 0.f, 0.f, 0.f};
    float l_part = 0.f;

    stage(0, 0);

    for (int t = 0; t < trips; ++t) {
      const int cur = t & 1;
      asm volatile("s_waitcnt vmcnt(0)" ::: "memory");
      __builtin_amdgcn_s_barrier();
      __builtin_amdgcn_sched_barrier(0);
      // --- QK^T swapped: sc[nb] = P^T frag (rows kv, col q) ---
      f32x4 sc[4];
      #pragma unroll
      for (int nb = 0; nb < 4; ++nb) {
        sc[nb] = (f32x4){0.f, 0.f, 0.f, 0.f};
        const int r = nb * 16 + lrow;
        #pragma unroll
        for (int kc = 0; kc < 4; ++kc) {
          int ch = (kc * 4 + lgrp) ^ (r & 7);
          short8 kf = *reinterpret_cast<const short8*>(&ks[cur][r * 128 + ch * 8]);
          sc[nb] = __builtin_amdgcn_mfma_f32_16x16x32_bf16(kf, qf[kc], sc[nb], 0, 0, 0);
        }
      }
      if (t + 1 < trips) stage(cur ^ 1, (t + 1) * 64);
      // --- mask + exp2 (lane-local: kv = nb*16+lgrp*4+j, q = lrow) ---
      float p[4][4];
      if (t < trips - 1) {
        #pragma unroll
        for (int nb = 0; nb < 4; ++nb)
          #pragma unroll
          for (int j = 0; j < 4; ++j)
            p[nb][j] = exp2f(fminf(sc[nb][j] * scl2, 43.f));
      } else {
        #pragma unroll
        for (int nb = 0; nb < 4; ++nb) {
          if (nb < wave) {
            #pragma unroll
            for (int j = 0; j < 4; ++j)
              p[nb][j] = exp2f(fminf(sc[nb][j] * scl2, 43.f));
          } else if (nb == wave) {
            #pragma unroll
            for (int j = 0; j < 4; ++j)
              p[nb][j] = (lgrp * 4 + j <= lrow) ? exp2f(fminf(sc[nb][j] * scl2, 43.f)) : 0.f;
          } else {
            #pragma unroll
            for (int j = 0; j < 4; ++j) p[nb][j] = 0.f;
          }
        }
      }
      #pragma unroll
      for (int nb = 0; nb < 4; ++nb)
        #pragma unroll
        for (int j = 0; j < 4; ++j) l_part += p[nb][j];
      // --- pack to bf16 pairs ---
      unsigned pk[4][2];
      #pragma unroll
      for (int nb = 0; nb < 4; ++nb) {
        pk[nb][0] = cvt_pk_bf16(p[nb][0], p[nb][1]);
        pk[nb][1] = cvt_pk_bf16(p[nb][2], p[nb][3]);
      }
      // --- redistribute to B-frag layout ---
      short8 pfB[2];
      #pragma unroll
      for (int half = 0; half < 2; ++half) {
        unsigned lo0 = __shfl(pk[2 * half][0], srcA), hi0 = __shfl(pk[2 * half + 1][0], srcA);
        unsigned lo1 = __shfl(pk[2 * half][1], srcA), hi1 = __shfl(pk[2 * half + 1][1], srcA);
        unsigned lo2 = __shfl(pk[2 * half][0], srcB), hi2 = __shfl(pk[2 * half + 1][0], srcB);
        unsigned lo3 = __shfl(pk[2 * half][1], srcB), hi3 = __shfl(pk[2 * half + 1][1], srcB);
        union { unsigned u[4]; short8 s8; } asm_u;
        asm_u.u[0] = hiSel ? hi0 : lo0;
        asm_u.u[1] = hiSel ? hi1 : lo1;
        asm_u.u[2] = hiSel ? hi2 : lo2;
        asm_u.u[3] = hiSel ? hi3 : lo3;
        pfB[half] = asm_u.s8;
      }
      // --- PV: acc^T[d][q] += V^T[d][kv] * P[q][kv] ---
      #pragma unroll
      for (int n = 0; n < 8; ++n) {
        const int d = n * 16 + lrow;
        #pragma unroll
        for (int kc2 = 0; kc2 < 2; ++kc2) {
          int ch = (kc2 * 4 + lgrp) ^ (d & 7);
          short8 vf = *reinterpret_cast<const short8*>(&vs[cur][d * 64 + ch * 8]);
          acc[n] = __builtin_amdgcn_mfma_f32_16x16x32_bf16(vf, pfB[kc2], acc[n], 0, 0, 0);
        }
      }
    }

    // reduce l over the 4 lgrp partners of this q, normalize, packed 8B stores
    float s = l_part;
    s += __shfl_xor(s, 16);
    s += __shfl_xor(s, 32);
    float inv = 1.f / s;
    u16* obase = o + (((size_t)(b * S + q0 + lrow)) * NH + h) * D;
    #pragma unroll
    for (int n = 0; n < 8; ++n) {
      uint2 wv;
      wv.x = cvt_pk_bf16(acc[n][0] * inv, acc[n][1] * inv);
      wv.y = cvt_pk_bf16(acc[n][2] * inv, acc[n][3] * inv);
      *reinterpret_cast<uint2*>(obase + n * 16 + lgrp * 4) = wv;
    }
    __syncthreads();                        // phase A fully drained before phase B restages
  }
}

// ---------------- launch ----------------
extern "C" void kernel_launch(void* const* d_in, const int* in_sizes, int n_in,
                              void* d_out, int out_size, void* d_ws, size_t ws_size,
                              hipStream_t stream) {
  const float* hs = (const float*)d_in[0];
  const float* Wq = (const float*)d_in[1];
  const float* Wk = (const float*)d_in[2];
  const float* Wv = (const float*)d_in[3];
  const float* Wo = (const float*)d_in[4];
  float* out = (float*)d_out;

  constexpr int B = 2, S = 2048, H = 2048, NH = 16, NKV = 8, D = 128;
  constexpr int M = B * S;  // 4096
  constexpr int NQKV = 4096;

  char* w = (char*)d_ws;
  auto alloc = [&](size_t bytes) { char* p = w; w += (bytes + 255) & ~(size_t)255; return p; };
  u16* hs_bf   = (u16*)alloc((size_t)M * H * 2);        // reused as attn later
  u16* wqkv_bf = (u16*)alloc((size_t)NQKV * H * 2);     // reused as vt+kt later
  u16* wo_bf   = (u16*)alloc((size_t)H * H * 2);
  u16* qkv     = (u16*)alloc((size_t)M * NQKV * 2);
  float* cosT  = (float*)alloc((size_t)S * 64 * 4);
  float* sinT  = (float*)alloc((size_t)S * 64 * 4);
  u16* attn = hs_bf;                                    // hs dead after QKV GEMM
  u16* vt   = wqkv_bf;                                  // 8MB
  u16* kt   = wqkv_bf + (size_t)B * NKV * D * S;        // next 8MB (Wqkv slot = 16MB)

  // fused casts (hs + Wq/Wk/Wv concatenated + Wo) in ONE launch
  cast_all_k<<<5242880 / 256, 256, 0, stream>>>(
      (const float4*)hs, (const float4*)Wq, (const float4*)Wk, (const float4*)Wv,
      (const float4*)Wo, hs_bf, wqkv_bf, wo_bf);
  rope_tables_k<<<(S * 64) / 256, 256, 0, stream>>>(cosT, sinT);

  // fused QKV projection: qkv[M][4096] (4-phase counted-vmcnt kernel, r18 version)
  gemm256p_k<u16><<<dim3(NQKV / 256, M / 256), 512, 0, stream>>>(hs_bf, wqkv_bf, qkv, M, NQKV, H);

  // K rope+repack AND V transpose in one launch (Q roped inside flash)
  prep_kv_k<<<8448, 256, 0, stream>>>(qkv, kt, vt, cosT, sinT);

  // attention (writes into old hs slot)
  flash_attn_k<<<512, 256, 0, stream>>>(qkv, kt, vt, attn, cosT, sinT);

  // output projection (fp32 out): 256x128 tile -> 256 blocks (full chip)
  gemm256_k<float, 128><<<dim3(H / 128, M / 256), 512, 0, stream>>>(attn, wo_bf, out, M, H, H);
}